// Round 8
// baseline (219.467 us; speedup 1.0000x reference)
//
#include <hip/hip_runtime.h>
#include <cstdint>
#include <cstddef>

// Sizes: B=16, T=8, K=4, DIN=9408, H1=1024, F=512, MH=128

typedef float f2_t __attribute__((ext_vector_type(2)));
typedef float f4_t __attribute__((ext_vector_type(4)));

// ---------------- 4x4 average pool: x(16,3,224,224) -> xp(16,9408) ----------------
__global__ void pool_kernel(const float* __restrict__ x, float* __restrict__ xp) {
  int idx = blockIdx.x * 256 + threadIdx.x;      // 150528 total
  int bc = idx / 3136;
  int r  = idx - bc * 3136;
  int i  = r / 56;
  int j  = r - i * 56;
  const float* src = x + ((size_t)bc * 224 + 4 * i) * 224 + 4 * j;
  float s = 0.f;
#pragma unroll
  for (int rr = 0; rr < 4; ++rr) {
    float4 v = *reinterpret_cast<const float4*>(src + rr * 224);
    s += v.x + v.y + v.z + v.w;
  }
  xp[idx] = s * 0.0625f;
}

// ---------------- split-K skinny GEMM (M=16), software-pipelined ----------------
// C[b,j] = sum_k A'[b,k]*B[k,j]; A' optionally scaled by coefs4[b*32+t*4] (seg1 only).
// Partials: P[chunk][16][N]. blockIdx.x = chunk c, .y = j-group.
// chunksPerT>0: iLoc0 wraps per t. Chunks >= chunkSplit: (A2,ldA2,B2), unscaled.
template<int KC, int VEC, int UF, int NT>
__global__ __launch_bounds__(256) void skinny_gemm(
    const float* __restrict__ A, int ldA,
    const float* __restrict__ B,
    const float* __restrict__ A2, int ldA2,
    const float* __restrict__ B2,
    int chunkSplit, int chunksPerT,
    const float* __restrict__ coefs4,
    int N, float* __restrict__ P)
{
  static_assert(KC % UF == 0, "");
  constexpr int NG = KC / UF;
  static_assert(NG >= 2, "");
  __shared__ float a_s[KC * 20];   // [kk][b], stride 20; comp reads broadcast
  const int c = blockIdx.x, tid = threadIdx.x;

  const float* Ab;
  const float* Bb;
  int lda, iLoc0, t = 0;
  bool scaled = false;
  if (c < chunkSplit) {
    Ab = A; lda = ldA;
    if (chunksPerT > 0) {
      t = c / chunksPerT;
      iLoc0 = (c - t * chunksPerT) * KC;
    } else {
      iLoc0 = c * KC;
    }
    scaled = (coefs4 != nullptr);
    Bb = B + (size_t)c * KC * N;
  } else {
    Ab = A2; lda = ldA2;
    iLoc0 = (c - chunkSplit) * KC;
    Bb = B2 + (size_t)iLoc0 * N;
  }

  for (int b = 0; b < 16; ++b) {
    float s = scaled ? coefs4[b * 32 + t * 4] : 1.f;
    const float* Arow = Ab + (size_t)b * lda + iLoc0;
    for (int kk = tid; kk < KC; kk += 256)
      a_s[kk * 20 + b] = s * Arow[kk];
  }
  __syncthreads();

  const int j0 = (blockIdx.y * 256 + tid) * VEC;
  const float* Brow = Bb + j0;

  float acc[16][VEC];
#pragma unroll
  for (int b = 0; b < 16; ++b)
#pragma unroll
    for (int v = 0; v < VEC; ++v) acc[b][v] = 0.f;

  float w0[UF][VEC], w1[UF][VEC];

  auto loadg = [&](float (&W)[UF][VEC], int kb) {
#pragma unroll
    for (int u = 0; u < UF; ++u) {
      const float* p = Brow + (size_t)(kb + u) * N;
      if constexpr (VEC == 2) {
        f2_t v;
        if constexpr (NT) v = __builtin_nontemporal_load(reinterpret_cast<const f2_t*>(p));
        else              v = *reinterpret_cast<const f2_t*>(p);
        W[u][0] = v.x; W[u][1] = v.y;
      } else {
        f4_t v;
        if constexpr (NT) v = __builtin_nontemporal_load(reinterpret_cast<const f4_t*>(p));
        else              v = *reinterpret_cast<const f4_t*>(p);
        W[u][0] = v.x; W[u][1] = v.y; W[u][2] = v.z; W[u][3] = v.w;
      }
    }
  };
  auto comp = [&](const float (&W)[UF][VEC], int kb) {
#pragma unroll
    for (int u = 0; u < UF; ++u) {
      int kk = kb + u;
      const float4 a0 = *reinterpret_cast<const float4*>(&a_s[kk * 20 + 0]);
      const float4 a1 = *reinterpret_cast<const float4*>(&a_s[kk * 20 + 4]);
      const float4 a2 = *reinterpret_cast<const float4*>(&a_s[kk * 20 + 8]);
      const float4 a3 = *reinterpret_cast<const float4*>(&a_s[kk * 20 + 12]);
      const float av[16] = {a0.x, a0.y, a0.z, a0.w, a1.x, a1.y, a1.z, a1.w,
                            a2.x, a2.y, a2.z, a2.w, a3.x, a3.y, a3.z, a3.w};
#pragma unroll
      for (int b = 0; b < 16; ++b)
#pragma unroll
        for (int v = 0; v < VEC; ++v)
          acc[b][v] = fmaf(av[b], W[u][v], acc[b][v]);
    }
  };

  loadg(w0, 0);
  if constexpr (NG % 2 == 0) {
#pragma unroll 1
    for (int g = 0; g + 2 < NG; g += 2) {
      loadg(w1, (g + 1) * UF);
      comp(w0, g * UF);
      loadg(w0, (g + 2) * UF);
      comp(w1, (g + 1) * UF);
    }
    loadg(w1, (NG - 1) * UF);
    comp(w0, (NG - 2) * UF);
    comp(w1, (NG - 1) * UF);
  } else {
#pragma unroll 1
    for (int g = 0; g + 3 < NG; g += 2) {
      loadg(w1, (g + 1) * UF);
      comp(w0, g * UF);
      loadg(w0, (g + 2) * UF);
      comp(w1, (g + 1) * UF);
    }
    loadg(w1, (NG - 2) * UF);
    comp(w0, (NG - 3) * UF);
    loadg(w0, (NG - 1) * UF);
    comp(w1, (NG - 2) * UF);
    comp(w0, (NG - 1) * UF);
  }

  float* Pb = P + (size_t)c * 16 * N + j0;
#pragma unroll
  for (int b = 0; b < 16; ++b) {
    if constexpr (VEC == 2) {
      *reinterpret_cast<float2*>(Pb) = make_float2(acc[b][0], acc[b][1]);
    } else {
      *reinterpret_cast<float4*>(Pb) = make_float4(acc[b][0], acc[b][1], acc[b][2], acc[b][3]);
    }
    Pb += N;
  }
}

// ---------------- fused reduce + epilogue (float4, 16 slices x 16 col-threads) --------
// Block covers 64 f-cols. Thread (fl,s): sums CPS=NCH/16 chunks of float4.
// MODE 1: z1,t1=(+b1,relu)  2: unused  3: h=relu(z1+cW1-scaled-sum+db1 term)  4: out
template<int NCH, int MODE, int FTOT>
__global__ __launch_bounds__(256) void reduce4(
    const float* __restrict__ P,
    const float* __restrict__ bias,      // b1(M1), z1(M3), b2(M4)
    const float* __restrict__ coefs,
    const float* __restrict__ dvec,      // db1(M3), db2(M4)
    float* __restrict__ o1, float* __restrict__ o2)
{
  constexpr int CPS = NCH / 16;
  static_assert(NCH % 16 == 0, "");
  __shared__ float4 r[16][17];
  const int fl = threadIdx.x & 15, s = threadIdx.x >> 4;
  const int f = blockIdx.x * 64 + fl * 4;

  const float4* p = reinterpret_cast<const float4*>(P + (size_t)s * CPS * FTOT + f);
  float sx = 0.f, sy = 0.f, sz = 0.f, sw = 0.f;
#pragma unroll 8
  for (int cc = 0; cc < CPS; ++cc) {
    float4 v = *p;
    sx += v.x; sy += v.y; sz += v.z; sw += v.w;
    p += FTOT / 4;
  }
  if constexpr (MODE == 3) {
    int b = f >> 10;
    float sc = coefs[b * 32 + (s >> 1) * 4];   // cW1[b, t = s/2]  (2 slices per t)
    sx *= sc; sy *= sc; sz *= sc; sw *= sc;
  }
  r[s][fl] = make_float4(sx, sy, sz, sw);
  __syncthreads();

  if (s == 0) {
    float vx = 0.f, vy = 0.f, vz = 0.f, vw = 0.f;
#pragma unroll
    for (int i = 0; i < 16; ++i) {
      float4 t = r[i][fl];
      vx += t.x; vy += t.y; vz += t.z; vw += t.w;
    }
    if constexpr (MODE == 1) {
      float4 bb = *reinterpret_cast<const float4*>(bias + (f & 1023));
      float4 z = make_float4(vx + bb.x, vy + bb.y, vz + bb.z, vw + bb.w);
      *reinterpret_cast<float4*>(o1 + f) = z;
      *reinterpret_cast<float4*>(o2 + f) =
          make_float4(fmaxf(z.x, 0.f), fmaxf(z.y, 0.f), fmaxf(z.z, 0.f), fmaxf(z.w, 0.f));
    } else if constexpr (MODE == 3) {
      int b = f >> 10, j = f & 1023;
      float4 zz = *reinterpret_cast<const float4*>(bias + f);   // z1
      float zx = vx + zz.x, zy = vy + zz.y, zzc = vz + zz.z, zw = vw + zz.w;
#pragma unroll
      for (int t = 0; t < 8; ++t) {
        float c1 = coefs[b * 32 + t * 4 + 1];
        float4 d = *reinterpret_cast<const float4*>(dvec + t * 1024 + j);
        zx = fmaf(c1, d.x, zx); zy = fmaf(c1, d.y, zy);
        zzc = fmaf(c1, d.z, zzc); zw = fmaf(c1, d.w, zw);
      }
      *reinterpret_cast<float4*>(o1 + f) =
          make_float4(fmaxf(zx, 0.f), fmaxf(zy, 0.f), fmaxf(zzc, 0.f), fmaxf(zw, 0.f));
    } else {
      int b = f >> 9, k = f & 511;
      float4 bb = *reinterpret_cast<const float4*>(bias + k);   // b2
      float zx = vx + bb.x, zy = vy + bb.y, zzc = vz + bb.z, zw = vw + bb.w;
#pragma unroll
      for (int t = 0; t < 8; ++t) {
        float c3 = coefs[b * 32 + t * 4 + 3];
        float4 d = *reinterpret_cast<const float4*>(dvec + t * 512 + k);
        zx = fmaf(c3, d.x, zx); zy = fmaf(c3, d.y, zy);
        zzc = fmaf(c3, d.z, zzc); zw = fmaf(c3, d.w, zw);
      }
      *reinterpret_cast<float4*>(o1 + f) = make_float4(zx, zy, zzc, zw);
    }
  }
}

// ---------------- tail: base = t1[b]@W2+b2 (LDS), m = relu(base@mW1+mb1), coefs = m@mW2+mb2
// One block per batch row b (16 blocks x 256 threads). W2 re-read per block stays L3-resident.
__global__ __launch_bounds__(256) void tail_kernel(
    const float* __restrict__ t1, const float* __restrict__ W2, const float* __restrict__ b2,
    const float* __restrict__ mW1, const float* __restrict__ mb1,
    const float* __restrict__ mW2, const float* __restrict__ mb2,
    float* __restrict__ coefs)
{
  __shared__ float ts[1024];
  __shared__ float bs[512];
  __shared__ float ms[128];
  const int b = blockIdx.x, tid = threadIdx.x;

  for (int i = tid; i < 1024; i += 256) ts[i] = t1[b * 1024 + i];
  __syncthreads();

  float a0 = b2[tid], a1 = b2[tid + 256];
#pragma unroll 8
  for (int k = 0; k < 1024; ++k) {
    float tv = ts[k];
    a0 = fmaf(tv, W2[k * 512 + tid],       a0);
    a1 = fmaf(tv, W2[k * 512 + tid + 256], a1);
  }
  bs[tid] = a0;
  bs[tid + 256] = a1;
  __syncthreads();

  if (tid < 128) {
    float m0 = 0.f, m1 = 0.f, m2 = 0.f, m3 = 0.f;
    for (int k = 0; k < 512; k += 4) {
      m0 = fmaf(bs[k + 0], mW1[(k + 0) * 128 + tid], m0);
      m1 = fmaf(bs[k + 1], mW1[(k + 1) * 128 + tid], m1);
      m2 = fmaf(bs[k + 2], mW1[(k + 2) * 128 + tid], m2);
      m3 = fmaf(bs[k + 3], mW1[(k + 3) * 128 + tid], m3);
    }
    ms[tid] = fmaxf(mb1[tid] + (m0 + m1) + (m2 + m3), 0.f);
  }
  __syncthreads();

  if (tid < 32) {
    float acc = mb2[tid];
    for (int k = 0; k < 128; ++k) acc = fmaf(ms[k], mW2[k * 32 + tid], acc);
    coefs[b * 32 + tid] = acc;
  }
}

extern "C" void kernel_launch(void* const* d_in, const int* in_sizes, int n_in,
                              void* d_out, int out_size, void* d_ws, size_t ws_size,
                              hipStream_t stream) {
  const float* x   = (const float*)d_in[0];
  const float* W1  = (const float*)d_in[1];
  const float* b1  = (const float*)d_in[2];
  const float* W2  = (const float*)d_in[3];
  const float* b2  = (const float*)d_in[4];
  const float* dW1 = (const float*)d_in[5];
  const float* db1 = (const float*)d_in[6];
  const float* dW2 = (const float*)d_in[7];
  const float* db2 = (const float*)d_in[8];
  const float* mW1 = (const float*)d_in[9];
  const float* mb1 = (const float*)d_in[10];
  const float* mW2 = (const float*)d_in[11];
  const float* mb2 = (const float*)d_in[12];
  float* out = (float*)d_out;

  float* ws    = (float*)d_ws;
  float* xp    = ws;                 // 150528
  float* z1    = xp + 150528;        // 16384
  float* t1    = z1 + 16384;         // 16384
  float* coefs = t1 + 16384;         // 512
  float* h     = coefs + 512;        // 16384
  float* P1    = h + 16384;          // 112*16*1024 = 1835008
  float* P3    = P1 + 1835008;       // 256*16*1024 = 4194304
  float* P4    = P3 + 4194304;       // 288*16*512  = 2359296
  // total ~8.6M floats ~ 34 MB

  const int BIG = 1 << 30;

  // xp = pool(x)
  pool_kernel<<<588, 256, 0, stream>>>(x, xp);

  // G1: xp @ W1 -> P1.  112 chunks KC=84, 2 j-groups (VEC=2) = 224 blocks
  skinny_gemm<84, 2, 7, 1><<<dim3(112, 2), 256, 0, stream>>>(
      xp, 9408, W1, nullptr, 0, nullptr, BIG, 0, nullptr, 1024, P1);
  // R1 -> z1, t1
  reduce4<112, 1, 16384><<<256, 256, 0, stream>>>(P1, b1, nullptr, nullptr, z1, t1);

  // tail: G2 + R2 + mcoef fused -> coefs (16 blocks, one per b)
  tail_kernel<<<16, 256, 0, stream>>>(t1, W2, b2, mW1, mb1, mW2, mb2, coefs);

  // G3: xp @ dW1 -> P3 (unscaled; cW1 applied in R3).
  // 256 chunks KC=294 (32 per t), VEC=4 covers all 1024 cols. 1 block/CU.
  skinny_gemm<294, 4, 7, 1><<<dim3(256, 1), 256, 0, stream>>>(
      xp, 9408, dW1, nullptr, 0, nullptr, BIG, 32, nullptr, 1024, P3);
  // R3 (cW1 scale per slice) -> h
  reduce4<256, 3, 16384><<<256, 256, 0, stream>>>(P3, z1, coefs, db1, h, nullptr);

  // G4: h @ {dW2 scaled, W2} -> P4.  seg1: 256 chunks KC=32 (32/t); seg2: 32 chunks over W2
  skinny_gemm<32, 2, 8, 1><<<dim3(288, 1), 256, 0, stream>>>(
      h, 1024, dW2, h, 1024, W2, 256, 32, coefs + 2, 512, P4);
  // R4 -> out
  reduce4<288, 4, 8192><<<128, 256, 0, stream>>>(P4, b2, coefs, db2, out, nullptr);
}

// Round 9
// 159.297 us; speedup vs baseline: 1.3777x; 1.3777x over previous
//
#include <hip/hip_runtime.h>
#include <cstdint>
#include <cstddef>

// Sizes: B=16, T=8, K=4, DIN=9408, H1=1024, F=512, MH=128

typedef float f2_t __attribute__((ext_vector_type(2)));
typedef float f4_t __attribute__((ext_vector_type(4)));

// ---------------- 4x4 average pool: x(16,3,224,224) -> xp(16,9408) ----------------
__global__ void pool_kernel(const float* __restrict__ x, float* __restrict__ xp) {
  int idx = blockIdx.x * 256 + threadIdx.x;      // 150528 total
  int bc = idx / 3136;
  int r  = idx - bc * 3136;
  int i  = r / 56;
  int j  = r - i * 56;
  const float* src = x + ((size_t)bc * 224 + 4 * i) * 224 + 4 * j;
  float s = 0.f;
#pragma unroll
  for (int rr = 0; rr < 4; ++rr) {
    float4 v = *reinterpret_cast<const float4*>(src + rr * 224);
    s += v.x + v.y + v.z + v.w;
  }
  xp[idx] = s * 0.0625f;
}

// ---------------- split-K skinny GEMM (M=16), software-pipelined ----------------
// C[b,j] = sum_k A'[b,k]*B[k,j]; A' optionally scaled by coefs4[b*32+t*4] (seg1 only).
// Partials: P[chunk][16][N]. blockIdx.x = chunk c, .y = j-group.
// chunksPerT>0: iLoc0 wraps per t. Chunks >= chunkSplit: (A2,ldA2,B2), unscaled.
// NOTE (round-8 lesson): keep >= 2 waves/SIMD -- either 2 blocks/CU of 256 thr
// or 1 block/CU of 512 thr (BS param). 1 wave/SIMD costs ~2x on these streams.
template<int KC, int VEC, int UF, int NT, int BS>
__global__ __launch_bounds__(BS) void skinny_gemm(
    const float* __restrict__ A, int ldA,
    const float* __restrict__ B,
    const float* __restrict__ A2, int ldA2,
    const float* __restrict__ B2,
    int chunkSplit, int chunksPerT,
    const float* __restrict__ coefs4,
    int N, float* __restrict__ P)
{
  static_assert(KC % UF == 0, "");
  constexpr int NG = KC / UF;
  static_assert(NG >= 2, "");
  __shared__ float a_s[KC * 20];   // [kk][b], stride 20; comp reads broadcast
  const int c = blockIdx.x, tid = threadIdx.x;

  const float* Ab;
  const float* Bb;
  int lda, iLoc0, t = 0;
  bool scaled = false;
  if (c < chunkSplit) {
    Ab = A; lda = ldA;
    if (chunksPerT > 0) {
      t = c / chunksPerT;
      iLoc0 = (c - t * chunksPerT) * KC;
    } else {
      iLoc0 = c * KC;
    }
    scaled = (coefs4 != nullptr);
    Bb = B + (size_t)c * KC * N;
  } else {
    Ab = A2; lda = ldA2;
    iLoc0 = (c - chunkSplit) * KC;
    Bb = B2 + (size_t)iLoc0 * N;
  }

  for (int b = 0; b < 16; ++b) {
    float s = scaled ? coefs4[b * 32 + t * 4] : 1.f;
    const float* Arow = Ab + (size_t)b * lda + iLoc0;
    for (int kk = tid; kk < KC; kk += BS)
      a_s[kk * 20 + b] = s * Arow[kk];
  }
  __syncthreads();

  const int j0 = (blockIdx.y * BS + tid) * VEC;
  const float* Brow = Bb + j0;

  float acc[16][VEC];
#pragma unroll
  for (int b = 0; b < 16; ++b)
#pragma unroll
    for (int v = 0; v < VEC; ++v) acc[b][v] = 0.f;

  float w0[UF][VEC], w1[UF][VEC];

  auto loadg = [&](float (&W)[UF][VEC], int kb) {
#pragma unroll
    for (int u = 0; u < UF; ++u) {
      const float* p = Brow + (size_t)(kb + u) * N;
      if constexpr (VEC == 2) {
        f2_t v;
        if constexpr (NT) v = __builtin_nontemporal_load(reinterpret_cast<const f2_t*>(p));
        else              v = *reinterpret_cast<const f2_t*>(p);
        W[u][0] = v.x; W[u][1] = v.y;
      } else {
        f4_t v;
        if constexpr (NT) v = __builtin_nontemporal_load(reinterpret_cast<const f4_t*>(p));
        else              v = *reinterpret_cast<const f4_t*>(p);
        W[u][0] = v.x; W[u][1] = v.y; W[u][2] = v.z; W[u][3] = v.w;
      }
    }
  };
  auto comp = [&](const float (&W)[UF][VEC], int kb) {
#pragma unroll
    for (int u = 0; u < UF; ++u) {
      int kk = kb + u;
      const float4 a0 = *reinterpret_cast<const float4*>(&a_s[kk * 20 + 0]);
      const float4 a1 = *reinterpret_cast<const float4*>(&a_s[kk * 20 + 4]);
      const float4 a2 = *reinterpret_cast<const float4*>(&a_s[kk * 20 + 8]);
      const float4 a3 = *reinterpret_cast<const float4*>(&a_s[kk * 20 + 12]);
      const float av[16] = {a0.x, a0.y, a0.z, a0.w, a1.x, a1.y, a1.z, a1.w,
                            a2.x, a2.y, a2.z, a2.w, a3.x, a3.y, a3.z, a3.w};
#pragma unroll
      for (int b = 0; b < 16; ++b)
#pragma unroll
        for (int v = 0; v < VEC; ++v)
          acc[b][v] = fmaf(av[b], W[u][v], acc[b][v]);
    }
  };

  loadg(w0, 0);
  if constexpr (NG % 2 == 0) {
#pragma unroll 1
    for (int g = 0; g + 2 < NG; g += 2) {
      loadg(w1, (g + 1) * UF);
      comp(w0, g * UF);
      loadg(w0, (g + 2) * UF);
      comp(w1, (g + 1) * UF);
    }
    loadg(w1, (NG - 1) * UF);
    comp(w0, (NG - 2) * UF);
    comp(w1, (NG - 1) * UF);
  } else {
#pragma unroll 1
    for (int g = 0; g + 3 < NG; g += 2) {
      loadg(w1, (g + 1) * UF);
      comp(w0, g * UF);
      loadg(w0, (g + 2) * UF);
      comp(w1, (g + 1) * UF);
    }
    loadg(w1, (NG - 2) * UF);
    comp(w0, (NG - 3) * UF);
    loadg(w0, (NG - 1) * UF);
    comp(w1, (NG - 2) * UF);
    comp(w0, (NG - 1) * UF);
  }

  float* Pb = P + (size_t)c * 16 * N + j0;
#pragma unroll
  for (int b = 0; b < 16; ++b) {
    if constexpr (VEC == 2) {
      *reinterpret_cast<float2*>(Pb) = make_float2(acc[b][0], acc[b][1]);
    } else {
      *reinterpret_cast<float4*>(Pb) = make_float4(acc[b][0], acc[b][1], acc[b][2], acc[b][3]);
    }
    Pb += N;
  }
}

// ---------------- fused reduce + epilogue (float4, 16 slices x 16 col-threads) --------
// Block covers 64 f-cols. Thread (fl,s): sums CPS=NCH/16 chunks of float4.
// MODE 1: z1,t1=(+b1,relu)  3: h=relu(z1+cW1-scaled-sum+db1 term)  4: out
template<int NCH, int MODE, int FTOT>
__global__ __launch_bounds__(256) void reduce4(
    const float* __restrict__ P,
    const float* __restrict__ bias,      // b1(M1), z1(M3), b2(M4)
    const float* __restrict__ coefs,
    const float* __restrict__ dvec,      // db1(M3), db2(M4)
    float* __restrict__ o1, float* __restrict__ o2)
{
  constexpr int CPS = NCH / 16;
  static_assert(NCH % 16 == 0, "");
  __shared__ float4 r[16][17];
  const int fl = threadIdx.x & 15, s = threadIdx.x >> 4;
  const int f = blockIdx.x * 64 + fl * 4;

  const float4* p = reinterpret_cast<const float4*>(P + (size_t)s * CPS * FTOT + f);
  float sx = 0.f, sy = 0.f, sz = 0.f, sw = 0.f;
#pragma unroll 8
  for (int cc = 0; cc < CPS; ++cc) {
    float4 v = *p;
    sx += v.x; sy += v.y; sz += v.z; sw += v.w;
    p += FTOT / 4;
  }
  if constexpr (MODE == 3) {
    int b = f >> 10;
    float sc = coefs[b * 32 + (s >> 1) * 4];   // cW1[b, t = s/2]  (2 slices per t)
    sx *= sc; sy *= sc; sz *= sc; sw *= sc;
  }
  r[s][fl] = make_float4(sx, sy, sz, sw);
  __syncthreads();

  if (s == 0) {
    float vx = 0.f, vy = 0.f, vz = 0.f, vw = 0.f;
#pragma unroll
    for (int i = 0; i < 16; ++i) {
      float4 t = r[i][fl];
      vx += t.x; vy += t.y; vz += t.z; vw += t.w;
    }
    if constexpr (MODE == 1) {
      float4 bb = *reinterpret_cast<const float4*>(bias + (f & 1023));
      float4 z = make_float4(vx + bb.x, vy + bb.y, vz + bb.z, vw + bb.w);
      *reinterpret_cast<float4*>(o1 + f) = z;
      *reinterpret_cast<float4*>(o2 + f) =
          make_float4(fmaxf(z.x, 0.f), fmaxf(z.y, 0.f), fmaxf(z.z, 0.f), fmaxf(z.w, 0.f));
    } else if constexpr (MODE == 3) {
      int b = f >> 10, j = f & 1023;
      float4 zz = *reinterpret_cast<const float4*>(bias + f);   // z1
      float zx = vx + zz.x, zy = vy + zz.y, zzc = vz + zz.z, zw = vw + zz.w;
#pragma unroll
      for (int t = 0; t < 8; ++t) {
        float c1 = coefs[b * 32 + t * 4 + 1];
        float4 d = *reinterpret_cast<const float4*>(dvec + t * 1024 + j);
        zx = fmaf(c1, d.x, zx); zy = fmaf(c1, d.y, zy);
        zzc = fmaf(c1, d.z, zzc); zw = fmaf(c1, d.w, zw);
      }
      *reinterpret_cast<float4*>(o1 + f) =
          make_float4(fmaxf(zx, 0.f), fmaxf(zy, 0.f), fmaxf(zzc, 0.f), fmaxf(zw, 0.f));
    } else {
      int b = f >> 9, k = f & 511;
      float4 bb = *reinterpret_cast<const float4*>(bias + k);   // b2
      float zx = vx + bb.x, zy = vy + bb.y, zzc = vz + bb.z, zw = vw + bb.w;
#pragma unroll
      for (int t = 0; t < 8; ++t) {
        float c3 = coefs[b * 32 + t * 4 + 3];
        float4 d = *reinterpret_cast<const float4*>(dvec + t * 512 + k);
        zx = fmaf(c3, d.x, zx); zy = fmaf(c3, d.y, zy);
        zzc = fmaf(c3, d.z, zzc); zw = fmaf(c3, d.w, zw);
      }
      *reinterpret_cast<float4*>(o1 + f) = make_float4(zx, zy, zzc, zw);
    }
  }
}

// ---------------- tail: base = t1[b]@W2+b2, m = relu(base@mW1+mb1), coefs = m@mW2+mb2
// One block per batch row b, 1024 threads (16 waves/CU): first GEMM k-split 2-way
// (tid&511 = output col, tid>>9 = k-half of 512), LDS-combine, then coef MLP.
__global__ __launch_bounds__(1024) void tail_kernel(
    const float* __restrict__ t1, const float* __restrict__ W2, const float* __restrict__ b2,
    const float* __restrict__ mW1, const float* __restrict__ mb1,
    const float* __restrict__ mW2, const float* __restrict__ mb2,
    float* __restrict__ coefs)
{
  __shared__ float ts[1024];
  __shared__ float bs2[1024];
  __shared__ float bs[512];
  __shared__ float ms[128];
  const int b = blockIdx.x, tid = threadIdx.x;

  ts[tid] = t1[b * 1024 + tid];
  __syncthreads();

  const int og = tid & 511, kh = tid >> 9;
  float a = kh ? 0.f : b2[og];
  const int k0 = kh * 512;
#pragma unroll 8
  for (int k = 0; k < 512; ++k)
    a = fmaf(ts[k0 + k], W2[(size_t)(k0 + k) * 512 + og], a);
  bs2[tid] = a;
  __syncthreads();

  if (tid < 512) bs[tid] = bs2[tid] + bs2[tid + 512];
  __syncthreads();

  if (tid < 128) {
    float m0 = 0.f, m1 = 0.f, m2 = 0.f, m3 = 0.f;
    for (int k = 0; k < 512; k += 4) {
      m0 = fmaf(bs[k + 0], mW1[(k + 0) * 128 + tid], m0);
      m1 = fmaf(bs[k + 1], mW1[(k + 1) * 128 + tid], m1);
      m2 = fmaf(bs[k + 2], mW1[(k + 2) * 128 + tid], m2);
      m3 = fmaf(bs[k + 3], mW1[(k + 3) * 128 + tid], m3);
    }
    ms[tid] = fmaxf(mb1[tid] + (m0 + m1) + (m2 + m3), 0.f);
  }
  __syncthreads();

  if (tid < 32) {
    float acc = mb2[tid];
    for (int k = 0; k < 128; ++k) acc = fmaf(ms[k], mW2[k * 32 + tid], acc);
    coefs[b * 32 + tid] = acc;
  }
}

extern "C" void kernel_launch(void* const* d_in, const int* in_sizes, int n_in,
                              void* d_out, int out_size, void* d_ws, size_t ws_size,
                              hipStream_t stream) {
  const float* x   = (const float*)d_in[0];
  const float* W1  = (const float*)d_in[1];
  const float* b1  = (const float*)d_in[2];
  const float* W2  = (const float*)d_in[3];
  const float* b2  = (const float*)d_in[4];
  const float* dW1 = (const float*)d_in[5];
  const float* db1 = (const float*)d_in[6];
  const float* dW2 = (const float*)d_in[7];
  const float* db2 = (const float*)d_in[8];
  const float* mW1 = (const float*)d_in[9];
  const float* mb1 = (const float*)d_in[10];
  const float* mW2 = (const float*)d_in[11];
  const float* mb2 = (const float*)d_in[12];
  float* out = (float*)d_out;

  float* ws    = (float*)d_ws;
  float* xp    = ws;                 // 150528
  float* z1    = xp + 150528;        // 16384
  float* t1    = z1 + 16384;         // 16384
  float* coefs = t1 + 16384;         // 512
  float* h     = coefs + 512;        // 16384
  float* P1    = h + 16384;          // 224*16*1024 = 3670016
  float* P3    = P1 + 3670016;       // 256*16*1024 = 4194304
  float* P4    = P3 + 4194304;       // 288*16*512  = 2359296
  // total ~10.4M floats ~ 42 MB

  const int BIG = 1 << 30;

  // xp = pool(x)
  pool_kernel<<<588, 256, 0, stream>>>(x, xp);

  // G1: xp @ W1 -> P1.  224 chunks KC=42, 2 j-groups (VEC=2) = 448 blocks (2 blk/CU)
  skinny_gemm<42, 2, 7, 1, 256><<<dim3(224, 2), 256, 0, stream>>>(
      xp, 9408, W1, nullptr, 0, nullptr, BIG, 0, nullptr, 1024, P1);
  // R1 -> z1, t1
  reduce4<224, 1, 16384><<<256, 256, 0, stream>>>(P1, b1, nullptr, nullptr, z1, t1);

  // tail: G2 + R2 + mcoef fused -> coefs (16 blocks x 1024 thr)
  tail_kernel<<<16, 1024, 0, stream>>>(t1, W2, b2, mW1, mb1, mW2, mb2, coefs);

  // G3: xp @ dW1 -> P3 (unscaled; cW1 applied in R3).
  // 256 chunks KC=294 (32 per t), 512-thr blocks VEC=2 cover 1024 cols; 8 waves/CU.
  skinny_gemm<294, 2, 14, 1, 512><<<dim3(256, 1), 512, 0, stream>>>(
      xp, 9408, dW1, nullptr, 0, nullptr, BIG, 32, nullptr, 1024, P3);
  // R3 (cW1 scale per slice) -> h
  reduce4<256, 3, 16384><<<256, 256, 0, stream>>>(P3, z1, coefs, db1, h, nullptr);

  // G4: h @ {dW2 scaled, W2} -> P4.  seg1: 256 chunks KC=32 (32/t); seg2: 32 chunks over W2
  skinny_gemm<32, 2, 8, 1, 256><<<dim3(288, 1), 256, 0, stream>>>(
      h, 1024, dW2, h, 1024, W2, 256, 32, coefs + 2, 512, P4);
  // R4 -> out
  reduce4<288, 4, 8192><<<128, 256, 0, stream>>>(P4, b2, coefs, db2, out, nullptr);
}

// Round 10
// 133.298 us; speedup vs baseline: 1.6464x; 1.1950x over previous
//
#include <hip/hip_runtime.h>
#include <cstdint>
#include <cstddef>

// Sizes: B=16, T=8, K=4, DIN=9408, H1=1024, F=512, MH=128

typedef float f2_t __attribute__((ext_vector_type(2)));
typedef float f4_t __attribute__((ext_vector_type(4)));

// ---------------- 4x4 average pool: x(16,3,224,224) -> xp(16,9408) ----------------
__global__ void pool_kernel(const float* __restrict__ x, float* __restrict__ xp) {
  int idx = blockIdx.x * 256 + threadIdx.x;      // 150528 total
  int bc = idx / 3136;
  int r  = idx - bc * 3136;
  int i  = r / 56;
  int j  = r - i * 56;
  const float* src = x + ((size_t)bc * 224 + 4 * i) * 224 + 4 * j;
  float s = 0.f;
#pragma unroll
  for (int rr = 0; rr < 4; ++rr) {
    float4 v = *reinterpret_cast<const float4*>(src + rr * 224);
    s += v.x + v.y + v.z + v.w;
  }
  xp[idx] = s * 0.0625f;
}

// ---------------- software-pipelined GEMM inner pipe (shared by all GEMMs) ----------
// acc[b][v] += sum_{kk<KC} a_s[(row0+kk)*20+b] * B[kk][j]  (B rows stride N)
template<int KC, int VEC, int UF, int NT>
__device__ __forceinline__ void gemm_pipe(
    const float* a_s, int row0, const float* Brow, int N, float (&acc)[16][VEC])
{
  static_assert(KC % UF == 0, "");
  constexpr int NG = KC / UF;
  static_assert(NG >= 2, "");
  float w0[UF][VEC], w1[UF][VEC];

  auto loadg = [&](float (&W)[UF][VEC], int kb) {
#pragma unroll
    for (int u = 0; u < UF; ++u) {
      const float* p = Brow + (size_t)(kb + u) * N;
      if constexpr (VEC == 2) {
        f2_t v;
        if constexpr (NT) v = __builtin_nontemporal_load(reinterpret_cast<const f2_t*>(p));
        else              v = *reinterpret_cast<const f2_t*>(p);
        W[u][0] = v.x; W[u][1] = v.y;
      } else {
        f4_t v;
        if constexpr (NT) v = __builtin_nontemporal_load(reinterpret_cast<const f4_t*>(p));
        else              v = *reinterpret_cast<const f4_t*>(p);
        W[u][0] = v.x; W[u][1] = v.y; W[u][2] = v.z; W[u][3] = v.w;
      }
    }
  };
  auto comp = [&](const float (&W)[UF][VEC], int kb) {
#pragma unroll
    for (int u = 0; u < UF; ++u) {
      int kk = row0 + kb + u;
      const float4 a0 = *reinterpret_cast<const float4*>(&a_s[kk * 20 + 0]);
      const float4 a1 = *reinterpret_cast<const float4*>(&a_s[kk * 20 + 4]);
      const float4 a2 = *reinterpret_cast<const float4*>(&a_s[kk * 20 + 8]);
      const float4 a3 = *reinterpret_cast<const float4*>(&a_s[kk * 20 + 12]);
      const float av[16] = {a0.x, a0.y, a0.z, a0.w, a1.x, a1.y, a1.z, a1.w,
                            a2.x, a2.y, a2.z, a2.w, a3.x, a3.y, a3.z, a3.w};
#pragma unroll
      for (int b = 0; b < 16; ++b)
#pragma unroll
        for (int v = 0; v < VEC; ++v)
          acc[b][v] = fmaf(av[b], W[u][v], acc[b][v]);
    }
  };

  loadg(w0, 0);
  if constexpr (NG % 2 == 0) {
#pragma unroll 1
    for (int g = 0; g + 2 < NG; g += 2) {
      loadg(w1, (g + 1) * UF);
      comp(w0, g * UF);
      loadg(w0, (g + 2) * UF);
      comp(w1, (g + 1) * UF);
    }
    loadg(w1, (NG - 1) * UF);
    comp(w0, (NG - 2) * UF);
    comp(w1, (NG - 1) * UF);
  } else {
#pragma unroll 1
    for (int g = 0; g + 3 < NG; g += 2) {
      loadg(w1, (g + 1) * UF);
      comp(w0, g * UF);
      loadg(w0, (g + 2) * UF);
      comp(w1, (g + 1) * UF);
    }
    loadg(w1, (NG - 2) * UF);
    comp(w0, (NG - 3) * UF);
    loadg(w0, (NG - 1) * UF);
    comp(w1, (NG - 2) * UF);
    comp(w0, (NG - 1) * UF);
  }
}

// ---------------- split-K skinny GEMM (M=16) -- used for G2, G4 ----------------
// NOTE (round-8 lesson): keep >= 2 waves/SIMD (2 blocks/CU of 256 thr).
template<int KC, int VEC, int UF, int NT, int BS>
__global__ __launch_bounds__(BS) void skinny_gemm(
    const float* __restrict__ A, int ldA,
    const float* __restrict__ B,
    const float* __restrict__ A2, int ldA2,
    const float* __restrict__ B2,
    int chunkSplit, int chunksPerT,
    const float* __restrict__ coefs4,
    int N, float* __restrict__ P)
{
  __shared__ float a_s[KC * 20];
  const int c = blockIdx.x, tid = threadIdx.x;

  const float* Ab;
  const float* Bb;
  int lda, iLoc0, t = 0;
  bool scaled = false;
  if (c < chunkSplit) {
    Ab = A; lda = ldA;
    if (chunksPerT > 0) {
      t = c / chunksPerT;
      iLoc0 = (c - t * chunksPerT) * KC;
    } else {
      iLoc0 = c * KC;
    }
    scaled = (coefs4 != nullptr);
    Bb = B + (size_t)c * KC * N;
  } else {
    Ab = A2; lda = ldA2;
    iLoc0 = (c - chunkSplit) * KC;
    Bb = B2 + (size_t)iLoc0 * N;
  }

  for (int b = 0; b < 16; ++b) {
    float s = scaled ? coefs4[b * 32 + t * 4] : 1.f;
    const float* Arow = Ab + (size_t)b * lda + iLoc0;
    for (int kk = tid; kk < KC; kk += BS)
      a_s[kk * 20 + b] = s * Arow[kk];
  }
  __syncthreads();

  const int j0 = (blockIdx.y * BS + tid) * VEC;
  float acc[16][VEC];
#pragma unroll
  for (int b = 0; b < 16; ++b)
#pragma unroll
    for (int v = 0; v < VEC; ++v) acc[b][v] = 0.f;

  gemm_pipe<KC, VEC, UF, NT>(a_s, 0, Bb + j0, N, acc);

  float* Pb = P + (size_t)c * 16 * N + j0;
#pragma unroll
  for (int b = 0; b < 16; ++b) {
    if constexpr (VEC == 2) {
      f2_t v = {acc[b][0], acc[b][1]};
      __builtin_nontemporal_store(v, reinterpret_cast<f2_t*>(Pb));
    } else {
      f4_t v = {acc[b][0], acc[b][1], acc[b][2], acc[b][3]};
      __builtin_nontemporal_store(v, reinterpret_cast<f4_t*>(Pb));
    }
    Pb += N;
  }
}

// ---------------- fused G1 + G3 (both depend only on xp) ----------------
// Blocks [0,224):   G1 chunk c: KC=42, VEC=2, 512 thr cover all 1024 cols -> P1[c]
// Blocks [224,480): G3 chunk c: KC=294 split 147/147 across wave-halves, VEC=4,
//                   LDS-combine -> P3[c] (16.8 MB partials at 16 B/lane loads).
// LDS 90 KB -> exactly 1 block/CU, 8 waves = 2 waves/SIMD.
__global__ __launch_bounds__(512, 2) void gbig_kernel(
    const float* __restrict__ xp,
    const float* __restrict__ W1,
    const float* __restrict__ dW1,
    float* __restrict__ P1, float* __restrict__ P3)
{
  __shared__ float a_s[294 * 20];    // 23.5 KB
  __shared__ float lds2[256 * 65];   // 66.6 KB (stride 65: conflict-free scalar r/w)
  const int tid = threadIdx.x;

  if (blockIdx.x < 224) {
    // ---- G1 ----
    const int c = blockIdx.x;
    for (int b = 0; b < 16; ++b) {
      const float* Arow = xp + (size_t)b * 9408 + c * 42;
      for (int kk = tid; kk < 42; kk += 512) a_s[kk * 20 + b] = Arow[kk];
    }
    __syncthreads();

    const int j0 = tid * 2;
    float acc[16][2];
#pragma unroll
    for (int b = 0; b < 16; ++b) { acc[b][0] = 0.f; acc[b][1] = 0.f; }
    gemm_pipe<42, 2, 7, 1>(a_s, 0, W1 + (size_t)c * 42 * 1024 + j0, 1024, acc);

    float* Pb = P1 + (size_t)c * 16 * 1024 + j0;
#pragma unroll
    for (int b = 0; b < 16; ++b) {
      f2_t v = {acc[b][0], acc[b][1]};
      __builtin_nontemporal_store(v, reinterpret_cast<f2_t*>(Pb));
      Pb += 1024;
    }
  } else {
    // ---- G3 ----
    const int c = blockIdx.x - 224;
    const int t = c >> 5, il = (c & 31) * 294;
    for (int b = 0; b < 16; ++b) {
      const float* Arow = xp + (size_t)b * 9408 + il;
      for (int kk = tid; kk < 294; kk += 512) a_s[kk * 20 + b] = Arow[kk];
    }
    __syncthreads();

    const int half = tid >> 8, t256 = tid & 255;
    const int j0 = t256 * 4;
    float acc[16][4];
#pragma unroll
    for (int b = 0; b < 16; ++b)
#pragma unroll
      for (int v = 0; v < 4; ++v) acc[b][v] = 0.f;

    gemm_pipe<147, 4, 7, 1>(a_s, half * 147,
                            dW1 + ((size_t)t * 9408 + il + half * 147) * 1024 + j0,
                            1024, acc);

    if (half) {
      float* dst = &lds2[t256 * 65];
#pragma unroll
      for (int b = 0; b < 16; ++b)
#pragma unroll
        for (int v = 0; v < 4; ++v) dst[b * 4 + v] = acc[b][v];
    }
    __syncthreads();
    if (!half) {
      const float* src = &lds2[t256 * 65];
      float* Pb = P3 + (size_t)c * 16 * 1024 + j0;
#pragma unroll
      for (int b = 0; b < 16; ++b) {
        f4_t v = {acc[b][0] + src[b * 4 + 0], acc[b][1] + src[b * 4 + 1],
                  acc[b][2] + src[b * 4 + 2], acc[b][3] + src[b * 4 + 3]};
        __builtin_nontemporal_store(v, reinterpret_cast<f4_t*>(Pb));
        Pb += 1024;
      }
    }
  }
}

// ---------------- fused reduce + epilogue (float4 NT loads, 16 slices x 16 cols) ------
// MODE 1: z1,t1=(+b1,relu)  3: h=relu(z1+cW1-scaled-sum+db1 term)  4: out
template<int NCH, int MODE, int FTOT>
__global__ __launch_bounds__(256) void reduce4(
    const float* __restrict__ P,
    const float* __restrict__ bias,      // b1(M1), z1(M3), b2(M4)
    const float* __restrict__ coefs,
    const float* __restrict__ dvec,      // db1(M3), db2(M4)
    float* __restrict__ o1, float* __restrict__ o2)
{
  constexpr int CPS = NCH / 16;
  static_assert(NCH % 16 == 0, "");
  __shared__ float4 r[16][17];
  const int fl = threadIdx.x & 15, s = threadIdx.x >> 4;
  const int f = blockIdx.x * 64 + fl * 4;

  const f4_t* p = reinterpret_cast<const f4_t*>(P + (size_t)s * CPS * FTOT + f);
  float sx = 0.f, sy = 0.f, sz = 0.f, sw = 0.f;
#pragma unroll 8
  for (int cc = 0; cc < CPS; ++cc) {
    f4_t v = __builtin_nontemporal_load(p);
    sx += v.x; sy += v.y; sz += v.z; sw += v.w;
    p += FTOT / 4;
  }
  if constexpr (MODE == 3) {
    int b = f >> 10;
    float sc = coefs[b * 32 + (s >> 1) * 4];   // cW1[b, t = s/2] (2 slices per t)
    sx *= sc; sy *= sc; sz *= sc; sw *= sc;
  }
  r[s][fl] = make_float4(sx, sy, sz, sw);
  __syncthreads();

  if (s == 0) {
    float vx = 0.f, vy = 0.f, vz = 0.f, vw = 0.f;
#pragma unroll
    for (int i = 0; i < 16; ++i) {
      float4 t = r[i][fl];
      vx += t.x; vy += t.y; vz += t.z; vw += t.w;
    }
    if constexpr (MODE == 1) {
      float4 bb = *reinterpret_cast<const float4*>(bias + (f & 1023));
      float4 z = make_float4(vx + bb.x, vy + bb.y, vz + bb.z, vw + bb.w);
      *reinterpret_cast<float4*>(o1 + f) = z;
      *reinterpret_cast<float4*>(o2 + f) =
          make_float4(fmaxf(z.x, 0.f), fmaxf(z.y, 0.f), fmaxf(z.z, 0.f), fmaxf(z.w, 0.f));
    } else if constexpr (MODE == 3) {
      int b = f >> 10, j = f & 1023;
      float4 zz = *reinterpret_cast<const float4*>(bias + f);   // z1
      float zx = vx + zz.x, zy = vy + zz.y, zzc = vz + zz.z, zw = vw + zz.w;
#pragma unroll
      for (int t = 0; t < 8; ++t) {
        float c1 = coefs[b * 32 + t * 4 + 1];
        float4 d = *reinterpret_cast<const float4*>(dvec + t * 1024 + j);
        zx = fmaf(c1, d.x, zx); zy = fmaf(c1, d.y, zy);
        zzc = fmaf(c1, d.z, zzc); zw = fmaf(c1, d.w, zw);
      }
      *reinterpret_cast<float4*>(o1 + f) =
          make_float4(fmaxf(zx, 0.f), fmaxf(zy, 0.f), fmaxf(zzc, 0.f), fmaxf(zw, 0.f));
    } else {
      int b = f >> 9, k = f & 511;
      float4 bb = *reinterpret_cast<const float4*>(bias + k);   // b2
      float zx = vx + bb.x, zy = vy + bb.y, zzc = vz + bb.z, zw = vw + bb.w;
#pragma unroll
      for (int t = 0; t < 8; ++t) {
        float c3 = coefs[b * 32 + t * 4 + 3];
        float4 d = *reinterpret_cast<const float4*>(dvec + t * 512 + k);
        zx = fmaf(c3, d.x, zx); zy = fmaf(c3, d.y, zy);
        zzc = fmaf(c3, d.z, zzc); zw = fmaf(c3, d.w, zw);
      }
      *reinterpret_cast<float4*>(o1 + f) = make_float4(zx, zy, zzc, zw);
    }
  }
}

// ---------------- tail2: R2 + mcoef fused. One block per b (16 x 512 thr). ----------
// base[b][k] = b2[k] + sum_c P2[c][b][k];  m = relu(base@mW1+mb1);  coefs = m@mW2+mb2
__global__ __launch_bounds__(512) void tail2_kernel(
    const float* __restrict__ P2, const float* __restrict__ b2,
    const float* __restrict__ mW1, const float* __restrict__ mb1,
    const float* __restrict__ mW2, const float* __restrict__ mb2,
    float* __restrict__ coefs)
{
  __shared__ float bs[512];
  __shared__ float pm[4][129];
  __shared__ float ms[128];
  __shared__ float p3[16][33];
  const int b = blockIdx.x, tid = threadIdx.x;

  // phase 1: sum 128 chunks for column k = tid
  float s = b2[tid];
  const float* p = P2 + b * 512 + tid;
#pragma unroll 8
  for (int c = 0; c < 128; ++c) { s += *p; p += 8192; }
  bs[tid] = s;
  __syncthreads();

  // phase 2: m[col], k-split 4 ways
  {
    int col = tid & 127, kq = tid >> 7;
    const float* br = &bs[kq * 128];
    const float* w = mW1 + (size_t)(kq * 128) * 128 + col;
    float m0 = 0.f, m1 = 0.f, m2 = 0.f, m3 = 0.f;
    for (int k = 0; k < 128; k += 4) {
      m0 = fmaf(br[k + 0], w[(k + 0) * 128], m0);
      m1 = fmaf(br[k + 1], w[(k + 1) * 128], m1);
      m2 = fmaf(br[k + 2], w[(k + 2) * 128], m2);
      m3 = fmaf(br[k + 3], w[(k + 3) * 128], m3);
    }
    pm[kq][col] = (m0 + m1) + (m2 + m3);
  }
  __syncthreads();
  if (tid < 128)
    ms[tid] = fmaxf(mb1[tid] + (pm[0][tid] + pm[1][tid]) + (pm[2][tid] + pm[3][tid]), 0.f);
  __syncthreads();

  // phase 3: coefs[o], k-split 16 ways (8 k each)
  {
    int o = tid & 31, kq = tid >> 5;
    float a = 0.f;
#pragma unroll
    for (int kk = 0; kk < 8; ++kk)
      a = fmaf(ms[kq * 8 + kk], mW2[(kq * 8 + kk) * 32 + o], a);
    p3[kq][o] = a;
  }
  __syncthreads();
  if (tid < 32) {
    float a = mb2[tid];
#pragma unroll
    for (int q = 0; q < 16; ++q) a += p3[q][tid];
    coefs[b * 32 + tid] = a;
  }
}

extern "C" void kernel_launch(void* const* d_in, const int* in_sizes, int n_in,
                              void* d_out, int out_size, void* d_ws, size_t ws_size,
                              hipStream_t stream) {
  const float* x   = (const float*)d_in[0];
  const float* W1  = (const float*)d_in[1];
  const float* b1  = (const float*)d_in[2];
  const float* W2  = (const float*)d_in[3];
  const float* b2  = (const float*)d_in[4];
  const float* dW1 = (const float*)d_in[5];
  const float* db1 = (const float*)d_in[6];
  const float* dW2 = (const float*)d_in[7];
  const float* db2 = (const float*)d_in[8];
  const float* mW1 = (const float*)d_in[9];
  const float* mb1 = (const float*)d_in[10];
  const float* mW2 = (const float*)d_in[11];
  const float* mb2 = (const float*)d_in[12];
  float* out = (float*)d_out;

  float* ws    = (float*)d_ws;
  float* xp    = ws;                 // 150528
  float* z1    = xp + 150528;        // 16384
  float* t1    = z1 + 16384;         // 16384
  float* coefs = t1 + 16384;         // 512
  float* h     = coefs + 512;        // 16384
  float* P1    = h + 16384;          // 224*16*1024 = 3670016
  float* P2    = P1 + 3670016;       // 128*16*512  = 1048576
  float* P3    = P2 + 1048576;       // 256*16*1024 = 4194304
  float* P4    = P3 + 4194304;       // 288*16*512  = 2359296
  // total ~11.5M floats ~ 46 MB

  const int BIG = 1 << 30;

  // 1) xp = pool(x)
  pool_kernel<<<588, 256, 0, stream>>>(x, xp);

  // 2) G1 (224 blks) + G3 (256 blks) fused: both depend only on xp
  gbig_kernel<<<480, 512, 0, stream>>>(xp, W1, dW1, P1, P3);

  // 3) R1 -> z1, t1
  reduce4<224, 1, 16384><<<256, 256, 0, stream>>>(P1, b1, nullptr, nullptr, z1, t1);

  // 4) G2: t1 @ W2 -> P2 (W2 streamed ONCE across 128 blocks; round-9 tail re-read it 16x)
  skinny_gemm<8, 2, 4, 0, 256><<<dim3(128, 1), 256, 0, stream>>>(
      t1, 1024, W2, nullptr, 0, nullptr, BIG, 0, nullptr, 512, P2);

  // 5) tail2: R2 + mcoef -> coefs
  tail2_kernel<<<16, 512, 0, stream>>>(P2, b2, mW1, mb1, mW2, mb2, coefs);

  // 6) R3 (cW1 scale per slice) -> h
  reduce4<256, 3, 16384><<<256, 256, 0, stream>>>(P3, z1, coefs, db1, h, nullptr);

  // 7) G4: h @ {dW2 scaled, W2} -> P4
  skinny_gemm<32, 2, 8, 1, 256><<<dim3(288, 1), 256, 0, stream>>>(
      h, 1024, dW2, h, 1024, W2, 256, 32, coefs + 2, 512, P4);

  // 8) R4 -> out
  reduce4<288, 4, 8192><<<128, 256, 0, stream>>>(P4, b2, coefs, db2, out, nullptr);
}

// Round 11
// 133.110 us; speedup vs baseline: 1.6488x; 1.0014x over previous
//
#include <hip/hip_runtime.h>
#include <cstdint>
#include <cstddef>

// Sizes: B=16, T=8, K=4, DIN=9408, H1=1024, F=512, MH=128

typedef float f2_t __attribute__((ext_vector_type(2)));
typedef float f4_t __attribute__((ext_vector_type(4)));

// ---------------- software-pipelined GEMM inner pipe ----------------
// acc[b][v] += sum_{kk<KC} a_s[(row0+kk)*20+b] * B[kk][j]  (B rows stride N)
template<int KC, int VEC, int UF, int NT>
__device__ __forceinline__ void gemm_pipe(
    const float* a_s, int row0, const float* Brow, int N, float (&acc)[16][VEC])
{
  static_assert(KC % UF == 0, "");
  constexpr int NG = KC / UF;
  static_assert(NG >= 2, "");
  float w0[UF][VEC], w1[UF][VEC];

  auto loadg = [&](float (&W)[UF][VEC], int kb) {
#pragma unroll
    for (int u = 0; u < UF; ++u) {
      const float* p = Brow + (size_t)(kb + u) * N;
      if constexpr (VEC == 2) {
        f2_t v;
        if constexpr (NT) v = __builtin_nontemporal_load(reinterpret_cast<const f2_t*>(p));
        else              v = *reinterpret_cast<const f2_t*>(p);
        W[u][0] = v.x; W[u][1] = v.y;
      } else {
        f4_t v;
        if constexpr (NT) v = __builtin_nontemporal_load(reinterpret_cast<const f4_t*>(p));
        else              v = *reinterpret_cast<const f4_t*>(p);
        W[u][0] = v.x; W[u][1] = v.y; W[u][2] = v.z; W[u][3] = v.w;
      }
    }
  };
  auto comp = [&](const float (&W)[UF][VEC], int kb) {
#pragma unroll
    for (int u = 0; u < UF; ++u) {
      int kk = row0 + kb + u;
      const float4 a0 = *reinterpret_cast<const float4*>(&a_s[kk * 20 + 0]);
      const float4 a1 = *reinterpret_cast<const float4*>(&a_s[kk * 20 + 4]);
      const float4 a2 = *reinterpret_cast<const float4*>(&a_s[kk * 20 + 8]);
      const float4 a3 = *reinterpret_cast<const float4*>(&a_s[kk * 20 + 12]);
      const float av[16] = {a0.x, a0.y, a0.z, a0.w, a1.x, a1.y, a1.z, a1.w,
                            a2.x, a2.y, a2.z, a2.w, a3.x, a3.y, a3.z, a3.w};
#pragma unroll
      for (int b = 0; b < 16; ++b)
#pragma unroll
        for (int v = 0; v < VEC; ++v)
          acc[b][v] = fmaf(av[b], W[u][v], acc[b][v]);
    }
  };

  loadg(w0, 0);
  if constexpr (NG % 2 == 0) {
#pragma unroll 1
    for (int g = 0; g + 2 < NG; g += 2) {
      loadg(w1, (g + 1) * UF);
      comp(w0, g * UF);
      loadg(w0, (g + 2) * UF);
      comp(w1, (g + 1) * UF);
    }
    loadg(w1, (NG - 1) * UF);
    comp(w0, (NG - 2) * UF);
    comp(w1, (NG - 1) * UF);
  } else {
#pragma unroll 1
    for (int g = 0; g + 3 < NG; g += 2) {
      loadg(w1, (g + 1) * UF);
      comp(w0, g * UF);
      loadg(w0, (g + 2) * UF);
      comp(w1, (g + 1) * UF);
    }
    loadg(w1, (NG - 2) * UF);
    comp(w0, (NG - 3) * UF);
    loadg(w0, (NG - 1) * UF);
    comp(w1, (NG - 2) * UF);
    comp(w0, (NG - 1) * UF);
  }
}

// ---------------- pooled A-chunk staging straight from x ----------------
// a_s[kk*20+b] = mean16(x[b, ch(il+kk), 4pi.., 4pj..]); consecutive tid ->
// consecutive kk -> consecutive pj -> coalesced 16B loads.
template<int KC, int NTHR>
__device__ __forceinline__ void stage_pool(float* a_s, const float* __restrict__ x, int il) {
  for (int idx = threadIdx.x; idx < 16 * KC; idx += NTHR) {
    int b = idx / KC, kk = idx - b * KC;
    int i = il + kk;
    int ch = i / 3136, r = i - ch * 3136;
    int pi = r / 56, pj = r - pi * 56;
    const float* src = x + ((size_t)(b * 3 + ch) * 224 + 4 * pi) * 224 + 4 * pj;
    float4 v0 = *reinterpret_cast<const float4*>(src);
    float4 v1 = *reinterpret_cast<const float4*>(src + 224);
    float4 v2 = *reinterpret_cast<const float4*>(src + 448);
    float4 v3 = *reinterpret_cast<const float4*>(src + 672);
    float s = (v0.x + v0.y + v0.z + v0.w) + (v1.x + v1.y + v1.z + v1.w)
            + (v2.x + v2.y + v2.z + v2.w) + (v3.x + v3.y + v3.z + v3.w);
    a_s[kk * 20 + b] = s * 0.0625f;
  }
}

// ---------------- gbig: pool + G1 + G3 fused (all depend only on x) ----------------
// Blocks [0,112):   G1 chunk c: KC=84, VEC=2, 512 thr cover 1024 cols -> P1[c]
// Blocks [112,368): G3 chunk c: KC=294 split 147/147 across wave-halves, VEC=4,
//                   LDS-combine -> P3[c].  LDS 90 KB -> 1 block/CU, 2 waves/SIMD.
__global__ __launch_bounds__(512, 2) void gbig_kernel(
    const float* __restrict__ x,
    const float* __restrict__ W1,
    const float* __restrict__ dW1,
    float* __restrict__ P1, float* __restrict__ P3)
{
  __shared__ float a_s[294 * 20];    // 23.5 KB
  __shared__ float lds2[256 * 65];   // 66.6 KB
  const int tid = threadIdx.x;

  if (blockIdx.x < 112) {
    // ---- G1 ----
    const int c = blockIdx.x;
    stage_pool<84, 512>(a_s, x, c * 84);
    __syncthreads();

    const int j0 = tid * 2;
    float acc[16][2];
#pragma unroll
    for (int b = 0; b < 16; ++b) { acc[b][0] = 0.f; acc[b][1] = 0.f; }
    gemm_pipe<84, 2, 7, 1>(a_s, 0, W1 + (size_t)c * 84 * 1024 + j0, 1024, acc);

    float* Pb = P1 + (size_t)c * 16 * 1024 + j0;
#pragma unroll
    for (int b = 0; b < 16; ++b) {
      f2_t v = {acc[b][0], acc[b][1]};
      __builtin_nontemporal_store(v, reinterpret_cast<f2_t*>(Pb));
      Pb += 1024;
    }
  } else {
    // ---- G3 ----
    const int c = blockIdx.x - 112;
    const int t = c >> 5, il = (c & 31) * 294;
    stage_pool<294, 512>(a_s, x, il);
    __syncthreads();

    const int half = tid >> 8, t256 = tid & 255;
    const int j0 = t256 * 4;
    float acc[16][4];
#pragma unroll
    for (int b = 0; b < 16; ++b)
#pragma unroll
      for (int v = 0; v < 4; ++v) acc[b][v] = 0.f;

    gemm_pipe<147, 4, 7, 1>(a_s, half * 147,
                            dW1 + ((size_t)t * 9408 + il + half * 147) * 1024 + j0,
                            1024, acc);

    if (half) {
      float* dst = &lds2[t256 * 65];
#pragma unroll
      for (int b = 0; b < 16; ++b)
#pragma unroll
        for (int v = 0; v < 4; ++v) dst[b * 4 + v] = acc[b][v];
    }
    __syncthreads();
    if (!half) {
      const float* src = &lds2[t256 * 65];
      float* Pb = P3 + (size_t)c * 16 * 1024 + j0;
#pragma unroll
      for (int b = 0; b < 16; ++b) {
        f4_t v = {acc[b][0] + src[b * 4 + 0], acc[b][1] + src[b * 4 + 1],
                  acc[b][2] + src[b * 4 + 2], acc[b][3] + src[b * 4 + 3]};
        __builtin_nontemporal_store(v, reinterpret_cast<f4_t*>(Pb));
        Pb += 1024;
      }
    }
  }
}

// ---------------- rg12: R1 + G2 fused. 256 blocks x 256 thr ----------------
// Block (b=blk>>4, jg=blk&15): reduce P1 over 112 chunks for 64 cols -> z1 (global),
// t1 (LDS). Then G2 row-b: stream W2[64 rows jg*64..][512] -> P2[jg][b][512].
// W2 slice is shared by the 16 b-blocks via L2/L3 (HBM reads W2 once).
__global__ __launch_bounds__(256) void rg12_kernel(
    const float* __restrict__ P1, const float* __restrict__ b1,
    const float* __restrict__ W2,
    float* __restrict__ z1, float* __restrict__ P2)
{
  __shared__ float4 r[16][17];
  __shared__ float t1s[64];
  const int blk = blockIdx.x;
  const int b = blk >> 4, jg = blk & 15;
  const int fl = threadIdx.x & 15, s = threadIdx.x >> 4;
  const int f = blk * 64 + fl * 4;          // = b*1024 + jg*64 + fl*4

  const f4_t* p = reinterpret_cast<const f4_t*>(P1 + (size_t)s * 7 * 16384 + f);
  float sx = 0.f, sy = 0.f, sz = 0.f, sw = 0.f;
#pragma unroll
  for (int cc = 0; cc < 7; ++cc) {
    f4_t v = __builtin_nontemporal_load(p);
    sx += v.x; sy += v.y; sz += v.z; sw += v.w;
    p += 4096;                              // 16384/4
  }
  r[s][fl] = make_float4(sx, sy, sz, sw);
  __syncthreads();

  if (s == 0) {
    float vx = 0.f, vy = 0.f, vz = 0.f, vw = 0.f;
#pragma unroll
    for (int i = 0; i < 16; ++i) {
      float4 t = r[i][fl];
      vx += t.x; vy += t.y; vz += t.z; vw += t.w;
    }
    float4 bb = *reinterpret_cast<const float4*>(b1 + (f & 1023));
    float4 z = make_float4(vx + bb.x, vy + bb.y, vz + bb.z, vw + bb.w);
    *reinterpret_cast<float4*>(z1 + f) = z;
    *reinterpret_cast<float4*>(&t1s[fl * 4]) =
        make_float4(fmaxf(z.x, 0.f), fmaxf(z.y, 0.f), fmaxf(z.z, 0.f), fmaxf(z.w, 0.f));
  }
  __syncthreads();

  // G2 for row b: acc[j] = sum_{kk<64} t1s[kk] * W2[jg*64+kk][j]
  const int j = threadIdx.x * 2;
  const float* w = W2 + (size_t)(jg * 64) * 512 + j;
  float a0 = 0.f, a1 = 0.f;
#pragma unroll 8
  for (int kk = 0; kk < 64; ++kk) {
    f2_t wv = *reinterpret_cast<const f2_t*>(w);
    w += 512;
    float tv = t1s[kk];
    a0 = fmaf(tv, wv.x, a0);
    a1 = fmaf(tv, wv.y, a1);
  }
  f2_t o = {a0, a1};
  __builtin_nontemporal_store(o, reinterpret_cast<f2_t*>(P2 + ((size_t)jg * 16 + b) * 512 + j));
}

// ---------------- split-K skinny GEMM (M=16) -- used for G4 ----------------
template<int KC, int VEC, int UF, int NT, int BS>
__global__ __launch_bounds__(BS) void skinny_gemm(
    const float* __restrict__ A, int ldA,
    const float* __restrict__ B,
    const float* __restrict__ A2, int ldA2,
    const float* __restrict__ B2,
    int chunkSplit, int chunksPerT,
    const float* __restrict__ coefs4,
    int N, float* __restrict__ P)
{
  __shared__ float a_s[KC * 20];
  const int c = blockIdx.x, tid = threadIdx.x;

  const float* Ab;
  const float* Bb;
  int lda, iLoc0, t = 0;
  bool scaled = false;
  if (c < chunkSplit) {
    Ab = A; lda = ldA;
    if (chunksPerT > 0) {
      t = c / chunksPerT;
      iLoc0 = (c - t * chunksPerT) * KC;
    } else {
      iLoc0 = c * KC;
    }
    scaled = (coefs4 != nullptr);
    Bb = B + (size_t)c * KC * N;
  } else {
    Ab = A2; lda = ldA2;
    iLoc0 = (c - chunkSplit) * KC;
    Bb = B2 + (size_t)iLoc0 * N;
  }

  for (int b = 0; b < 16; ++b) {
    float s = scaled ? coefs4[b * 32 + t * 4] : 1.f;
    const float* Arow = Ab + (size_t)b * lda + iLoc0;
    for (int kk = tid; kk < KC; kk += BS)
      a_s[kk * 20 + b] = s * Arow[kk];
  }
  __syncthreads();

  const int j0 = (blockIdx.y * BS + tid) * VEC;
  float acc[16][VEC];
#pragma unroll
  for (int b = 0; b < 16; ++b)
#pragma unroll
    for (int v = 0; v < VEC; ++v) acc[b][v] = 0.f;

  gemm_pipe<KC, VEC, UF, NT>(a_s, 0, Bb + j0, N, acc);

  float* Pb = P + (size_t)c * 16 * N + j0;
#pragma unroll
  for (int b = 0; b < 16; ++b) {
    if constexpr (VEC == 2) {
      f2_t v = {acc[b][0], acc[b][1]};
      __builtin_nontemporal_store(v, reinterpret_cast<f2_t*>(Pb));
    } else {
      f4_t v = {acc[b][0], acc[b][1], acc[b][2], acc[b][3]};
      __builtin_nontemporal_store(v, reinterpret_cast<f4_t*>(Pb));
    }
    Pb += N;
  }
}

// ---------------- fused reduce + epilogue (float4 NT loads, 16 slices x 16 cols) ------
// MODE 3: h=relu(z1+cW1-scaled-sum+db1 term)   MODE 4: out
template<int NCH, int MODE, int FTOT>
__global__ __launch_bounds__(256) void reduce4(
    const float* __restrict__ P,
    const float* __restrict__ bias,      // z1(M3), b2(M4)
    const float* __restrict__ coefs,
    const float* __restrict__ dvec,      // db1(M3), db2(M4)
    float* __restrict__ o1)
{
  constexpr int CPS = NCH / 16;
  static_assert(NCH % 16 == 0, "");
  __shared__ float4 r[16][17];
  const int fl = threadIdx.x & 15, s = threadIdx.x >> 4;
  const int f = blockIdx.x * 64 + fl * 4;

  const f4_t* p = reinterpret_cast<const f4_t*>(P + (size_t)s * CPS * FTOT + f);
  float sx = 0.f, sy = 0.f, sz = 0.f, sw = 0.f;
#pragma unroll 8
  for (int cc = 0; cc < CPS; ++cc) {
    f4_t v = __builtin_nontemporal_load(p);
    sx += v.x; sy += v.y; sz += v.z; sw += v.w;
    p += FTOT / 4;
  }
  if constexpr (MODE == 3) {
    int b = f >> 10;
    float sc = coefs[b * 32 + (s >> 1) * 4];   // cW1[b, t = s/2] (2 slices per t)
    sx *= sc; sy *= sc; sz *= sc; sw *= sc;
  }
  r[s][fl] = make_float4(sx, sy, sz, sw);
  __syncthreads();

  if (s == 0) {
    float vx = 0.f, vy = 0.f, vz = 0.f, vw = 0.f;
#pragma unroll
    for (int i = 0; i < 16; ++i) {
      float4 t = r[i][fl];
      vx += t.x; vy += t.y; vz += t.z; vw += t.w;
    }
    if constexpr (MODE == 3) {
      int b = f >> 10, j = f & 1023;
      float4 zz = *reinterpret_cast<const float4*>(bias + f);   // z1
      float zx = vx + zz.x, zy = vy + zz.y, zzc = vz + zz.z, zw = vw + zz.w;
#pragma unroll
      for (int t = 0; t < 8; ++t) {
        float c1 = coefs[b * 32 + t * 4 + 1];
        float4 d = *reinterpret_cast<const float4*>(dvec + t * 1024 + j);
        zx = fmaf(c1, d.x, zx); zy = fmaf(c1, d.y, zy);
        zzc = fmaf(c1, d.z, zzc); zw = fmaf(c1, d.w, zw);
      }
      *reinterpret_cast<float4*>(o1 + f) =
          make_float4(fmaxf(zx, 0.f), fmaxf(zy, 0.f), fmaxf(zzc, 0.f), fmaxf(zw, 0.f));
    } else {
      int b = f >> 9, k = f & 511;
      float4 bb = *reinterpret_cast<const float4*>(bias + k);   // b2
      float zx = vx + bb.x, zy = vy + bb.y, zzc = vz + bb.z, zw = vw + bb.w;
#pragma unroll
      for (int t = 0; t < 8; ++t) {
        float c3 = coefs[b * 32 + t * 4 + 3];
        float4 d = *reinterpret_cast<const float4*>(dvec + t * 512 + k);
        zx = fmaf(c3, d.x, zx); zy = fmaf(c3, d.y, zy);
        zzc = fmaf(c3, d.z, zzc); zw = fmaf(c3, d.w, zw);
      }
      *reinterpret_cast<float4*>(o1 + f) = make_float4(zx, zy, zzc, zw);
    }
  }
}

// ---------------- tail2: R2 + mcoef fused. One block per b (16 x 512 thr). ----------
__global__ __launch_bounds__(512) void tail2_kernel(
    const float* __restrict__ P2, const float* __restrict__ b2,
    const float* __restrict__ mW1, const float* __restrict__ mb1,
    const float* __restrict__ mW2, const float* __restrict__ mb2,
    float* __restrict__ coefs)
{
  __shared__ float bs[512];
  __shared__ float pm[4][129];
  __shared__ float ms[128];
  __shared__ float p3[16][33];
  const int b = blockIdx.x, tid = threadIdx.x;

  // phase 1: base[b][k] = b2[k] + sum over 16 chunks
  float s = b2[tid];
  const float* p = P2 + b * 512 + tid;
#pragma unroll
  for (int c = 0; c < 16; ++c) { s += *p; p += 8192; }
  bs[tid] = s;
  __syncthreads();

  // phase 2: m[col], k-split 4 ways
  {
    int col = tid & 127, kq = tid >> 7;
    const float* br = &bs[kq * 128];
    const float* w = mW1 + (size_t)(kq * 128) * 128 + col;
    float m0 = 0.f, m1 = 0.f, m2 = 0.f, m3 = 0.f;
    for (int k = 0; k < 128; k += 4) {
      m0 = fmaf(br[k + 0], w[(k + 0) * 128], m0);
      m1 = fmaf(br[k + 1], w[(k + 1) * 128], m1);
      m2 = fmaf(br[k + 2], w[(k + 2) * 128], m2);
      m3 = fmaf(br[k + 3], w[(k + 3) * 128], m3);
    }
    pm[kq][col] = (m0 + m1) + (m2 + m3);
  }
  __syncthreads();
  if (tid < 128)
    ms[tid] = fmaxf(mb1[tid] + (pm[0][tid] + pm[1][tid]) + (pm[2][tid] + pm[3][tid]), 0.f);
  __syncthreads();

  // phase 3: coefs[o], k-split 16 ways
  {
    int o = tid & 31, kq = tid >> 5;
    float a = 0.f;
#pragma unroll
    for (int kk = 0; kk < 8; ++kk)
      a = fmaf(ms[kq * 8 + kk], mW2[(kq * 8 + kk) * 32 + o], a);
    p3[kq][o] = a;
  }
  __syncthreads();
  if (tid < 32) {
    float a = mb2[tid];
#pragma unroll
    for (int q = 0; q < 16; ++q) a += p3[q][tid];
    coefs[b * 32 + tid] = a;
  }
}

extern "C" void kernel_launch(void* const* d_in, const int* in_sizes, int n_in,
                              void* d_out, int out_size, void* d_ws, size_t ws_size,
                              hipStream_t stream) {
  const float* x   = (const float*)d_in[0];
  const float* W1  = (const float*)d_in[1];
  const float* b1  = (const float*)d_in[2];
  const float* W2  = (const float*)d_in[3];
  const float* b2  = (const float*)d_in[4];
  const float* dW1 = (const float*)d_in[5];
  const float* db1 = (const float*)d_in[6];
  const float* dW2 = (const float*)d_in[7];
  const float* db2 = (const float*)d_in[8];
  const float* mW1 = (const float*)d_in[9];
  const float* mb1 = (const float*)d_in[10];
  const float* mW2 = (const float*)d_in[11];
  const float* mb2 = (const float*)d_in[12];
  float* out = (float*)d_out;

  float* ws    = (float*)d_ws;
  float* z1    = ws;                 // 16384
  float* coefs = z1 + 16384;         // 512
  float* h     = coefs + 512;        // 16384
  float* P1    = h + 16384;          // 112*16*1024 = 1835008
  float* P2    = P1 + 1835008;       // 16*16*512   = 131072
  float* P3    = P2 + 131072;        // 256*16*1024 = 4194304
  float* P4    = P3 + 4194304;       // 288*16*512  = 2359296
  // total ~8.6M floats ~ 34 MB

  // 1) gbig: pool + G1 (112 blks) + G3 (256 blks), all from x
  gbig_kernel<<<368, 512, 0, stream>>>(x, W1, dW1, P1, P3);

  // 2) rg12: R1 + G2 -> z1, P2
  rg12_kernel<<<256, 256, 0, stream>>>(P1, b1, W2, z1, P2);

  // 3) tail2: R2 + mcoef -> coefs
  tail2_kernel<<<16, 512, 0, stream>>>(P2, b2, mW1, mb1, mW2, mb2, coefs);

  // 4) R3 (cW1 scale per slice) -> h
  reduce4<256, 3, 16384><<<256, 256, 0, stream>>>(P3, z1, coefs, db1, h);

  // 5) G4: h @ {dW2 scaled, W2} -> P4
  skinny_gemm<32, 2, 8, 1, 256><<<dim3(288, 1), 256, 0, stream>>>(
      h, 1024, dW2, h, 1024, W2, 256, 32, coefs + 2, 512, P4);

  // 6) R4 -> out
  reduce4<288, 4, 8192><<<128, 256, 0, stream>>>(P4, b2, coefs, db2, out);
}